// Round 1
// baseline (156.108 us; speedup 1.0000x reference)
//
#include <hip/hip_runtime.h>

#define A_N 33600
#define G_N 256
#define NC 80
#define KK 10

// Monotone float->uint mapping: preserves total order (incl. +/-inf).
__device__ __forceinline__ unsigned int ford(float f) {
    unsigned int u = __float_as_uint(f);
    return (u & 0x80000000u) ? ~u : (u | 0x80000000u);
}

// Per-anchor: logsum[a] = sum_c log_sigmoid(-s[a,c])  (one wave per anchor)
__global__ void k_logsum(const float* __restrict__ scores, float* __restrict__ logsum) {
    int t = blockIdx.x * blockDim.x + threadIdx.x;
    int wv = t >> 6;
    int lane = t & 63;
    if (wv >= A_N) return;
    const float* row = scores + (long)wv * NC;
    float acc = 0.f;
    for (int c = lane; c < NC; c += 64) {
        float s = row[c];
        float L = log1pf(expf(-fabsf(s)));
        acc -= (fmaxf(s, 0.f) + L);   // log_sigmoid(-s) = -(max(s,0)+L)
    }
    #pragma unroll
    for (int off = 32; off > 0; off >>= 1) acc += __shfl_down(acc, off);
    if (lane == 0) logsum[wv] = acc;
}

// One block per gt: scan all anchors, keep top-10 smallest cost (index tiebreak),
// count candidates (inside && iou>0).
__global__ __launch_bounds__(256) void k_topk(
    const float* __restrict__ scores, const float* __restrict__ pred_b,
    const float* __restrict__ anchors, const int* __restrict__ gt_labels,
    const float* __restrict__ gt_b, const float* __restrict__ logsum,
    int* __restrict__ topk_idx, int* __restrict__ ks)
{
    int g = blockIdx.x;
    int tid = threadIdx.x;
    float x1 = gt_b[g*4+0], y1 = gt_b[g*4+1], x2 = gt_b[g*4+2], y2 = gt_b[g*4+3];
    int label = gt_labels[g];
    float cx = (x1+x2)*0.5f, cy = (y1+y2)*0.5f;
    float rx = 2.5f*(x2-x1), ry = 2.5f*(y2-y1);
    float area_g = (x2-x1)*(y2-y1);

    unsigned long long best[KK];
    #pragma unroll
    for (int i = 0; i < KK; i++) best[i] = ~0ull;
    int count = 0;

    for (int a = tid; a < A_N; a += 256) {
        float4 pb = reinterpret_cast<const float4*>(pred_b)[a];
        float2 ap = reinterpret_cast<const float2*>(anchors)[a];
        bool in_gt = (ap.x >= x1) && (ap.x <= x2) && (ap.y >= y1) && (ap.y <= y2);
        bool in_c  = (ap.x >= cx-rx) && (ap.x <= cx+rx) && (ap.y >= cy-ry) && (ap.y <= cy+ry);
        bool inside = in_gt && in_c;

        float ltx = fmaxf(x1, pb.x), lty = fmaxf(y1, pb.y);
        float rbx = fminf(x2, pb.z), rby = fminf(y2, pb.w);
        float w = fmaxf(rbx-ltx, 0.f), h = fmaxf(rby-lty, 0.f);
        float overlap = w*h;
        float area_p = (pb.z-pb.x)*(pb.w-pb.y);
        float uni = area_g + area_p - overlap + 1e-6f;
        float iou = overlap/uni;

        if (inside && overlap > 0.f) count++;

        float s = scores[(long)a*NC + label];
        float L = log1pf(expf(-fabsf(s)));
        float logp   = -(fmaxf(-s, 0.f) + L);
        float log1mp = -(fmaxf( s, 0.f) + L);
        float cls = -(logp - log1mp) - logsum[a];
        float cost = cls + 3.0f*(-logf(iou)) + (inside ? 0.f : 1e10f);

        unsigned long long key = ((unsigned long long)ford(cost) << 32) | (unsigned int)a;
        if (key < best[KK-1]) {
            best[KK-1] = key;  // insert at end, bubble into place (all static idx)
            #pragma unroll
            for (int k = KK-1; k > 0; k--) {
                unsigned long long lo = best[k-1] < best[k] ? best[k-1] : best[k];
                unsigned long long hi = best[k-1] < best[k] ? best[k]   : best[k-1];
                best[k-1] = lo; best[k] = hi;
            }
        }
    }

    __shared__ unsigned long long lds[256*KK];
    __shared__ int scount;
    if (tid == 0) scount = 0;
    __syncthreads();
    atomicAdd(&scount, count);
    #pragma unroll
    for (int i = 0; i < KK; i++) lds[tid*KK + i] = best[i];
    __syncthreads();

    // pairwise merge of sorted 10-lists (each thread's list is fully populated:
    // 131+ candidates per thread >= 10)
    for (int s = 128; s >= 1; s >>= 1) {
        if (tid < s) {
            unsigned long long out[KK];
            unsigned long long* La = &lds[tid*KK];
            unsigned long long* Lb = &lds[(tid+s)*KK];
            int i = 0, j = 0;
            #pragma unroll
            for (int k = 0; k < KK; k++) {
                unsigned long long va = La[i], vb = Lb[j];
                if (va <= vb) { out[k] = va; i++; } else { out[k] = vb; j++; }
            }
            #pragma unroll
            for (int k = 0; k < KK; k++) La[k] = out[k];
        }
        __syncthreads();
    }

    if (tid < KK) topk_idx[g*KK + tid] = (int)(lds[tid] & 0xffffffffu);
    if (tid == 0) {
        int k = scount; if (k < 1) k = 1; if (k > KK) k = KK;
        ks[g] = k;
    }
}

__global__ void k_scatter(const int* __restrict__ topk_idx, const int* __restrict__ ks,
                          int* __restrict__ assigned) {
    int t = blockIdx.x * blockDim.x + threadIdx.x;
    if (t >= G_N*KK) return;
    int g = t / KK, j = t % KK;
    if (j < ks[g]) atomicMax(&assigned[topk_idx[t]], g);
}

__global__ void k_out(const int* __restrict__ assigned, const int* __restrict__ gt_labels,
                      const float* __restrict__ gt_b, const float* __restrict__ pred_b,
                      float* __restrict__ out_labels, float* __restrict__ out_bbox,
                      float* __restrict__ out_scores) {
    int a = blockIdx.x * blockDim.x + threadIdx.x;
    if (a >= A_N) return;
    int g = assigned[a];
    bool pos = g >= 0;
    int label = NC;
    float4 ob = make_float4(0.f, 0.f, 0.f, 0.f);
    float val = 0.f;
    if (pos) {
        label = gt_labels[g];
        float x1 = gt_b[g*4+0], y1 = gt_b[g*4+1], x2 = gt_b[g*4+2], y2 = gt_b[g*4+3];
        ob = make_float4(x1, y1, x2, y2);
        float4 pb = reinterpret_cast<const float4*>(pred_b)[a];
        float ltx = fmaxf(x1, pb.x), lty = fmaxf(y1, pb.y);
        float rbx = fminf(x2, pb.z), rby = fminf(y2, pb.w);
        float w = fmaxf(rbx-ltx, 0.f), h = fmaxf(rby-lty, 0.f);
        float overlap = w*h;
        float area_g = (x2-x1)*(y2-y1);
        float area_p = (pb.z-pb.x)*(pb.w-pb.y);
        float uni = area_g + area_p - overlap + 1e-6f;
        val = overlap/uni;
    }
    out_labels[a] = (float)label;
    reinterpret_cast<float4*>(out_bbox)[a] = ob;
    out_scores[(long)a*(NC+1) + label] = val;
}

extern "C" void kernel_launch(void* const* d_in, const int* in_sizes, int n_in,
                              void* d_out, int out_size, void* d_ws, size_t ws_size,
                              hipStream_t stream) {
    const float* pred_scores   = (const float*)d_in[0];
    const float* pred_bboxes   = (const float*)d_in[1];
    const float* anchor_points = (const float*)d_in[2];
    const int*   gt_labels     = (const int*)d_in[3];
    const float* gt_bboxes     = (const float*)d_in[4];

    char* ws = (char*)d_ws;
    float* logsum   = (float*)ws;                                // A floats
    int*   assigned = (int*)(ws + (size_t)A_N*4);                // A ints
    int*   topk_idx = (int*)(ws + (size_t)2*A_N*4);              // G*KK ints
    int*   ks       = (int*)(ws + (size_t)2*A_N*4 + G_N*KK*4);   // G ints

    float* out_labels = (float*)d_out;          // A
    float* out_bbox   = out_labels + A_N;       // A*4
    float* out_scores = out_bbox + 4*A_N;       // A*81

    hipMemsetAsync(assigned, 0xFF, (size_t)A_N*sizeof(int), stream);           // -1
    hipMemsetAsync(out_scores, 0, (size_t)A_N*(NC+1)*sizeof(float), stream);   // zeros

    k_logsum<<<A_N/4, 256, 0, stream>>>(pred_scores, logsum);
    k_topk<<<G_N, 256, 0, stream>>>(pred_scores, pred_bboxes, anchor_points,
                                    gt_labels, gt_bboxes, logsum, topk_idx, ks);
    k_scatter<<<(G_N*KK + 255)/256, 256, 0, stream>>>(topk_idx, ks, assigned);
    k_out<<<(A_N + 255)/256, 256, 0, stream>>>(assigned, gt_labels, gt_bboxes,
                                               pred_bboxes, out_labels, out_bbox, out_scores);
}

// Round 2
// 89.233 us; speedup vs baseline: 1.7494x; 1.7494x over previous
//
#include <hip/hip_runtime.h>

#define A_N 33600
#define G_N 256
#define NC 80
#define KK 10
#define SEG 16
#define SEG_LEN (A_N / SEG)   // 2100

// Monotone float->uint mapping: preserves total order (incl. +/-inf).
__device__ __forceinline__ unsigned int ford(float f) {
    unsigned int u = __float_as_uint(f);
    return (u & 0x80000000u) ? ~u : (u | 0x80000000u);
}

// Per-anchor: logsum[a] = sum_c log_sigmoid(-s[a,c])  (one wave per anchor)
__global__ void k_logsum(const float* __restrict__ scores, float* __restrict__ logsum) {
    int t = blockIdx.x * blockDim.x + threadIdx.x;
    int wv = t >> 6;
    int lane = t & 63;
    if (wv >= A_N) return;
    const float* row = scores + (long)wv * NC;
    float acc = 0.f;
    for (int c = lane; c < NC; c += 64) {
        float s = row[c];
        float L = log1pf(expf(-fabsf(s)));
        acc -= (fmaxf(s, 0.f) + L);   // log_sigmoid(-s) = -(max(s,0)+L)
    }
    #pragma unroll
    for (int off = 32; off > 0; off >>= 1) acc += __shfl_down(acc, off);
    if (lane == 0) logsum[wv] = acc;
}

// One block per (gt, segment): scan SEG_LEN anchors, keep partial top-10
// (global-index tiebreak via packed key) + partial candidate count.
__global__ __launch_bounds__(256) void k_topk_part(
    const float* __restrict__ scores, const float* __restrict__ pred_b,
    const float* __restrict__ anchors, const int* __restrict__ gt_labels,
    const float* __restrict__ gt_b, const float* __restrict__ logsum,
    unsigned long long* __restrict__ part, int* __restrict__ part_cnt)
{
    int bid = blockIdx.x;
    int g = bid >> 4;          // bid = g*SEG + seg
    int seg = bid & (SEG - 1);
    int tid = threadIdx.x;

    float x1 = gt_b[g*4+0], y1 = gt_b[g*4+1], x2 = gt_b[g*4+2], y2 = gt_b[g*4+3];
    int label = gt_labels[g];
    float cx = (x1+x2)*0.5f, cy = (y1+y2)*0.5f;
    float rx = 2.5f*(x2-x1), ry = 2.5f*(y2-y1);
    float area_g = (x2-x1)*(y2-y1);

    unsigned long long best[KK];
    #pragma unroll
    for (int i = 0; i < KK; i++) best[i] = ~0ull;
    int count = 0;

    int a0 = seg * SEG_LEN;
    for (int a = a0 + tid; a < a0 + SEG_LEN; a += 256) {
        float4 pb = reinterpret_cast<const float4*>(pred_b)[a];
        float2 ap = reinterpret_cast<const float2*>(anchors)[a];
        bool in_gt = (ap.x >= x1) && (ap.x <= x2) && (ap.y >= y1) && (ap.y <= y2);
        bool in_c  = (ap.x >= cx-rx) && (ap.x <= cx+rx) && (ap.y >= cy-ry) && (ap.y <= cy+ry);
        bool inside = in_gt && in_c;

        float ltx = fmaxf(x1, pb.x), lty = fmaxf(y1, pb.y);
        float rbx = fminf(x2, pb.z), rby = fminf(y2, pb.w);
        float w = fmaxf(rbx-ltx, 0.f), h = fmaxf(rby-lty, 0.f);
        float overlap = w*h;
        float area_p = (pb.z-pb.x)*(pb.w-pb.y);
        float uni = area_g + area_p - overlap + 1e-6f;
        float iou = overlap/uni;

        if (inside && overlap > 0.f) count++;

        // log_sigmoid(s) - log_sigmoid(-s) == s bit-exactly (shared log1p term
        // cancels), so cls_cost = -s - logsum[a].
        float s = scores[(long)a*NC + label];
        float cls = -s - logsum[a];
        float cost = cls + 3.0f*(-logf(iou)) + (inside ? 0.f : 1e10f);

        unsigned long long key = ((unsigned long long)ford(cost) << 32) | (unsigned int)a;
        if (key < best[KK-1]) {
            best[KK-1] = key;  // insert at end, bubble into place (all static idx)
            #pragma unroll
            for (int k = KK-1; k > 0; k--) {
                unsigned long long lo = best[k-1] < best[k] ? best[k-1] : best[k];
                unsigned long long hi = best[k-1] < best[k] ? best[k]   : best[k-1];
                best[k-1] = lo; best[k] = hi;
            }
        }
    }

    __shared__ unsigned long long lds[256*KK];
    __shared__ int scount;
    if (tid == 0) scount = 0;
    __syncthreads();
    atomicAdd(&scount, count);
    #pragma unroll
    for (int i = 0; i < KK; i++) lds[tid*KK + i] = best[i];
    __syncthreads();

    // pairwise merge of sorted 10-lists; ~0ull padding sorts last, harmless
    for (int s = 128; s >= 1; s >>= 1) {
        if (tid < s) {
            unsigned long long out[KK];
            unsigned long long* La = &lds[tid*KK];
            unsigned long long* Lb = &lds[(tid+s)*KK];
            int i = 0, j = 0;
            #pragma unroll
            for (int k = 0; k < KK; k++) {
                unsigned long long va = La[i], vb = Lb[j];
                if (va <= vb) { out[k] = va; i++; } else { out[k] = vb; j++; }
            }
            #pragma unroll
            for (int k = 0; k < KK; k++) La[k] = out[k];
        }
        __syncthreads();
    }

    if (tid < KK) part[(size_t)bid*KK + tid] = lds[tid];
    if (tid == 0) part_cnt[bid] = scount;
}

// One wave per gt: merge 16 partial top-10 lists, sum counts, scatter.
__global__ __launch_bounds__(64) void k_merge(
    const unsigned long long* __restrict__ part, const int* __restrict__ part_cnt,
    int* __restrict__ assigned)
{
    int g = blockIdx.x;
    int tid = threadIdx.x;
    __shared__ unsigned long long lds[SEG*KK];   // 160 entries
    __shared__ int sk;
    for (int i = tid; i < SEG*KK; i += 64) lds[i] = part[(size_t)g*SEG*KK + i];
    int cnt = (tid < SEG) ? part_cnt[g*SEG + tid] : 0;
    __syncthreads();

    for (int s = SEG/2; s >= 1; s >>= 1) {
        if (tid < s) {
            unsigned long long out[KK];
            unsigned long long* La = &lds[tid*KK];
            unsigned long long* Lb = &lds[(tid+s)*KK];
            int i = 0, j = 0;
            #pragma unroll
            for (int k = 0; k < KK; k++) {
                unsigned long long va = La[i], vb = Lb[j];
                if (va <= vb) { out[k] = va; i++; } else { out[k] = vb; j++; }
            }
            #pragma unroll
            for (int k = 0; k < KK; k++) La[k] = out[k];
        }
        __syncthreads();
    }

    #pragma unroll
    for (int off = 32; off > 0; off >>= 1) cnt += __shfl_down(cnt, off);
    if (tid == 0) {
        int k = cnt; if (k < 1) k = 1; if (k > KK) k = KK;
        sk = k;
    }
    __syncthreads();

    if (tid < sk) {
        int a = (int)(lds[tid] & 0xffffffffu);
        atomicMax(&assigned[a], g);
    }
}

__global__ void k_out(const int* __restrict__ assigned, const int* __restrict__ gt_labels,
                      const float* __restrict__ gt_b, const float* __restrict__ pred_b,
                      float* __restrict__ out_labels, float* __restrict__ out_bbox,
                      float* __restrict__ out_scores) {
    int a = blockIdx.x * blockDim.x + threadIdx.x;
    if (a >= A_N) return;
    int g = assigned[a];
    bool pos = g >= 0;
    int label = NC;
    float4 ob = make_float4(0.f, 0.f, 0.f, 0.f);
    float val = 0.f;
    if (pos) {
        label = gt_labels[g];
        float x1 = gt_b[g*4+0], y1 = gt_b[g*4+1], x2 = gt_b[g*4+2], y2 = gt_b[g*4+3];
        ob = make_float4(x1, y1, x2, y2);
        float4 pb = reinterpret_cast<const float4*>(pred_b)[a];
        float ltx = fmaxf(x1, pb.x), lty = fmaxf(y1, pb.y);
        float rbx = fminf(x2, pb.z), rby = fminf(y2, pb.w);
        float w = fmaxf(rbx-ltx, 0.f), h = fmaxf(rby-lty, 0.f);
        float overlap = w*h;
        float area_g = (x2-x1)*(y2-y1);
        float area_p = (pb.z-pb.x)*(pb.w-pb.y);
        float uni = area_g + area_p - overlap + 1e-6f;
        val = overlap/uni;
    }
    out_labels[a] = (float)label;
    reinterpret_cast<float4*>(out_bbox)[a] = ob;
    out_scores[(long)a*(NC+1) + label] = val;
}

extern "C" void kernel_launch(void* const* d_in, const int* in_sizes, int n_in,
                              void* d_out, int out_size, void* d_ws, size_t ws_size,
                              hipStream_t stream) {
    const float* pred_scores   = (const float*)d_in[0];
    const float* pred_bboxes   = (const float*)d_in[1];
    const float* anchor_points = (const float*)d_in[2];
    const int*   gt_labels     = (const int*)d_in[3];
    const float* gt_bboxes     = (const float*)d_in[4];

    char* ws = (char*)d_ws;
    unsigned long long* part = (unsigned long long*)ws;            // G*SEG*KK u64 (8B-aligned first)
    size_t part_bytes = (size_t)G_N*SEG*KK*8;
    float* logsum   = (float*)(ws + part_bytes);                   // A floats
    int*   assigned = (int*)(ws + part_bytes + (size_t)A_N*4);     // A ints
    int*   part_cnt = (int*)(ws + part_bytes + (size_t)2*A_N*4);   // G*SEG ints

    float* out_labels = (float*)d_out;          // A
    float* out_bbox   = out_labels + A_N;       // A*4
    float* out_scores = out_bbox + 4*A_N;       // A*81

    hipMemsetAsync(assigned, 0xFF, (size_t)A_N*sizeof(int), stream);           // -1
    hipMemsetAsync(out_scores, 0, (size_t)A_N*(NC+1)*sizeof(float), stream);   // zeros

    k_logsum<<<A_N/4, 256, 0, stream>>>(pred_scores, logsum);
    k_topk_part<<<G_N*SEG, 256, 0, stream>>>(pred_scores, pred_bboxes, anchor_points,
                                             gt_labels, gt_bboxes, logsum, part, part_cnt);
    k_merge<<<G_N, 64, 0, stream>>>(part, part_cnt, assigned);
    k_out<<<(A_N + 255)/256, 256, 0, stream>>>(assigned, gt_labels, gt_bboxes,
                                               pred_bboxes, out_labels, out_bbox, out_scores);
}